// Round 8
// baseline (533.835 us; speedup 1.0000x reference)
//
#include <hip/hip_runtime.h>
#include <stdint.h>

// CAFormer fused block, MI355X gfx950.
// R11 (on R10=338us, k_attn 102us):
//  - k_gx DELETED: conv blocks atomicAdd tile-sums into gxsum (conv already
//    stages x in LDS); cw multiply moved to k_final; gate runs after conv.
//  - k_rnorm DELETED: k_qkv epilogue reduces fp32 acc^2 per q/k row ->
//    atomicAdd rnsum (pre-bf16 values, closer to reference); k_attn rsqrts.
//  - k_zero (plain kernel) zeroes the 776-float scratch per invocation.
//  - k_final staging 2px/thread (float2/uint loads, 32 iters not 64).
// ws layout (160 MiB + 3104 B):
//   qkv bf16 [4][192][65536] @ 0          (100663296 B)
//   oh  bf16 [4][64][65536]  @ 100663296  (33554432 B)
//   ov  bf16                 @ 134217728  (33554432 B)
//   f32 scratch @ 167772160: gxsum[256] cwaw[8] rnsum[512]

typedef unsigned short u16;
typedef __attribute__((ext_vector_type(8))) short bf16x8;
typedef __attribute__((ext_vector_type(4))) float f32x4;

#define DEV static __device__ __forceinline__

DEV u16 f2bf(float f) {
  unsigned u = __float_as_uint(f);
  return (u16)((u + 0x7fffu + ((u >> 16) & 1u)) >> 16);
}
DEV float bf2f(u16 h) { return __uint_as_float(((unsigned)h) << 16); }

// barrier that orders LDS only: lgkmcnt(0) + raw s_barrier. Global loads in
// flight (thread-private regs) are NOT drained, unlike __syncthreads().
DEV void bar_lds() {
  asm volatile("s_waitcnt lgkmcnt(0)" ::: "memory");
  __builtin_amdgcn_s_barrier();
}

// ---------------- zero the f32 scratch (graph-capture-safe) ----------------
__global__ void k_zero(float* __restrict__ fs) {
  int t = threadIdx.x;
  if (t < 776) fs[t] = 0.f;
}

// ---------------- gating MLP -> cw/aw per batch ----------------
__global__ void k_gate(const float* __restrict__ gxsum, const float* __restrict__ g1w,
                       const float* __restrict__ g1b, const float* __restrict__ g2w,
                       const float* __restrict__ g2b, float* __restrict__ cwaw) {
  __shared__ float h1[4][16];
  int t = threadIdx.x;
  int b = t >> 4, j = t & 15;
  float a = g1b[j];
  for (int c = 0; c < 64; ++c) a += g1w[j * 64 + c] * gxsum[b * 64 + c] * (1.f / 65536.f);
  h1[b][j] = fmaxf(a, 0.f);
  __syncthreads();
  if (t < 4) {
    float l0 = g2b[0], l1 = g2b[1];
    for (int k = 0; k < 16; ++k) { l0 += g2w[k] * h1[t][k]; l1 += g2w[16 + k] * h1[t][k]; }
    float m = fmaxf(l0, l1);
    float e0 = __expf(l0 - m), e1 = __expf(l1 - m);
    float inv = 1.f / (e0 + e1);
    cwaw[t * 2 + 0] = e0 * inv;  // conv weight
    cwaw[t * 2 + 1] = e1 * inv;  // attn weight
  }
}

// ---------------- qkv projection GEMM + fused rnorm partial sums ----------------
__global__ __launch_bounds__(256) void k_qkv(const float* __restrict__ x,
                                             const float* __restrict__ wqkv,
                                             u16* __restrict__ qkv,
                                             float* __restrict__ rnsum) {
  __shared__ u16 Ws[192 * 72];  // A: [row][ch], stride 72 shorts
  __shared__ u16 Xs[128 * 72];  // B^T: [px][ch]
  int t = threadIdx.x;
  int b = blockIdx.x >> 9;
  int p0 = (blockIdx.x & 511) << 7;

  // stage wqkv (192x64 fp32 -> bf16)
  {
    int row = t >> 2, c0 = (t & 3) << 4;
#pragma unroll
    for (int i = 0; i < 3; ++i) {
      int r = i * 64 + row;
      const float* src = wqkv + r * 64 + c0;
      unsigned pk[8];
#pragma unroll
      for (int j = 0; j < 8; ++j)
        pk[j] = (unsigned)f2bf(src[2 * j]) | ((unsigned)f2bf(src[2 * j + 1]) << 16);
      uint4* dst = (uint4*)&Ws[r * 72 + c0];
      dst[0] = make_uint4(pk[0], pk[1], pk[2], pk[3]);
      dst[1] = make_uint4(pk[4], pk[5], pk[6], pk[7]);
    }
  }
  // stage x tile: 64ch x 128px, transposed -> Xs[px][ch]
  {
    int p = t & 127, ch = t >> 7;
    const float* xb = x + ((size_t)(b * 64) << 16) + p0 + p;
#pragma unroll
    for (int i = 0; i < 32; ++i) {
      int c = 2 * i + ch;
      Xs[p * 72 + c] = f2bf(xb[(size_t)c << 16]);
    }
  }
  __syncthreads();

  int w = t >> 6, l = t & 63, q = l >> 4, cl = l & 15;
  bf16x8 af[3][2];
#pragma unroll
  for (int g = 0; g < 3; ++g)
#pragma unroll
    for (int k = 0; k < 2; ++k)
      af[g][k] = *(const bf16x8*)&Ws[(w * 48 + g * 16 + cl) * 72 + k * 32 + q * 8];

  f32x4 acc[3][8];
  f32x4 zero = {0.f, 0.f, 0.f, 0.f};
#pragma unroll
  for (int g = 0; g < 3; ++g)
#pragma unroll
    for (int j = 0; j < 8; ++j) acc[g][j] = zero;

  for (int j = 0; j < 8; ++j) {
    bf16x8 b0 = *(const bf16x8*)&Xs[(j * 16 + cl) * 72 + q * 8];
    bf16x8 b1 = *(const bf16x8*)&Xs[(j * 16 + cl) * 72 + 32 + q * 8];
#pragma unroll
    for (int g = 0; g < 3; ++g) {
      acc[g][j] = __builtin_amdgcn_mfma_f32_16x16x32_bf16(af[g][0], b0, acc[g][j], 0, 0, 0);
      acc[g][j] = __builtin_amdgcn_mfma_f32_16x16x32_bf16(af[g][1], b1, acc[g][j], 0, 0, 0);
    }
  }
  u16* outb = qkv + ((size_t)(b * 192) << 16) + p0;
  for (int g = 0; g < 3; ++g) {
    int rowb = w * 48 + g * 16 + q * 4;
#pragma unroll
    for (int r = 0; r < 4; ++r) {
      u16* orow = outb + ((size_t)(rowb + r) << 16);
#pragma unroll
      for (int j = 0; j < 8; ++j) orow[j * 16 + cl] = f2bf(acc[g][j][r]);
    }
  }
  // fused rnorm: sum of squares of fp32 acc for q,k rows (row < 128)
  float* rn = rnsum + b * 128;
#pragma unroll
  for (int g = 0; g < 3; ++g) {
    int rowb = w * 48 + g * 16 + q * 4;
    if (rowb < 128) {
#pragma unroll
      for (int r = 0; r < 4; ++r) {
        float s = 0.f;
#pragma unroll
        for (int j = 0; j < 8; ++j) { float v = acc[g][j][r]; s += v * v; }
#pragma unroll
        for (int off = 1; off < 16; off <<= 1) s += __shfl_xor(s, off);
        if (cl == 0) atomicAdd(&rn[rowb + r], s);
      }
    }
  }
}

// ---------------- depthwise 3x3+5x5 conv (unscaled) + fused gx sums ----------------
__global__ void k_conv(const float* __restrict__ x, const float* __restrict__ w3,
                       const float* __restrict__ b3, const float* __restrict__ w5,
                       const float* __restrict__ b5, float* __restrict__ outmix,
                       float* __restrict__ gxsum) {
  int rt = blockIdx.x & 31, bc = blockIdx.x >> 5, c = bc & 63;
  int r0 = rt * 8;
  const float* xp = x + ((size_t)bc << 16);
  __shared__ float xs[12][260];  // padded: col g maps to index g+2; 0..1,258..259 zero
  __shared__ float redg[4];
  int y = threadIdx.x;
  for (int rr = 0; rr < 12; ++rr) {
    int gr = r0 - 2 + rr;
    xs[rr][y + 2] = (gr >= 0 && gr < 256) ? xp[(size_t)gr * 256 + y] : 0.f;
  }
  if (y < 2) {
    for (int rr = 0; rr < 12; ++rr) { xs[rr][y] = 0.f; xs[rr][258 + y] = 0.f; }
  }
  __syncthreads();
  float W3[9], W5[25];
#pragma unroll
  for (int i = 0; i < 9; ++i) W3[i] = w3[c * 9 + i];
#pragma unroll
  for (int i = 0; i < 25; ++i) W5[i] = w5[c * 25 + i];
  float bias = b3[c] + b5[c];
  float* op = outmix + ((size_t)bc << 16);
  for (int k = 0; k < 8; ++k) {
    float a = bias;
#pragma unroll
    for (int di = 0; di < 3; ++di)
#pragma unroll
      for (int dj = 0; dj < 3; ++dj)
        a += W3[di * 3 + dj] * xs[k + 1 + di][y + 1 + dj];
#pragma unroll
    for (int di = 0; di < 5; ++di)
#pragma unroll
      for (int dj = 0; dj < 5; ++dj)
        a += W5[di * 5 + dj] * xs[k + di][y + dj];
    op[(size_t)(r0 + k) * 256 + y] = a;
  }
  // fused gx: sum this block's 8x256 x-tile (rows r0..r0+7 always in-range)
  float s = 0.f;
#pragma unroll
  for (int k = 0; k < 8; ++k) s += xs[k + 2][y + 2];
  for (int off = 32; off; off >>= 1) s += __shfl_down(s, off);
  if ((y & 63) == 0) redg[y >> 6] = s;
  __syncthreads();
  if (y == 0) atomicAdd(&gxsum[bc], redg[0] + redg[1] + redg[2] + redg[3]);
}

// ---------------- axial attention, MFMA bf16, 64-row tiles, pipelined staging ----------------
// dir0: S direct (native Q,K rows); PV stages V^T per z-window (preloaded regs).
// dir1: S stages Q^T + K^T per y-window (preloaded regs); PV direct.
__global__ __launch_bounds__(256) void k_attn(
    const u16* __restrict__ qkv, const float* __restrict__ rnsum,
    const float* __restrict__ scale, u16* __restrict__ oh, u16* __restrict__ ov) {
  __shared__ __align__(16) unsigned char smem[54272];
  u16* Pls = (u16*)smem;                       // [64][264] bf16 (33792 B)
  unsigned* Qt32 = (unsigned*)smem;            // [64][20] u32 (5120 B; dir1 S, Pls dead)
  float* red = (float*)(smem + 33792);         // [4][64] f32
  unsigned* Tt32 = (unsigned*)(smem + 33792);  // [256][20] u32 (Kt dir1-S / Vt dir0-PV)
  float* Osf = (float*)smem;                   // [32][260] f32 (dir1 store; Pls dead)

  int t = threadIdx.x;
  int w = t >> 6, l = t & 63, q = l >> 4, cl = l & 15;
  // XCD-aware bijective swizzle: one channel's 8 blocks (4 rt x 2 dir) are
  // consecutive in idx -> same XCD -> planes shared in that XCD's L2.
  int idx = (blockIdx.x & 7) * 256 + (blockIdx.x >> 3);
  int rt = idx & 3, dir = (idx >> 2) & 1, c = (idx >> 3) & 63, b = idx >> 9;
  int r0 = rt << 6;

  const size_t P = 65536;
  const u16* Qp = qkv + (size_t)(b * 192 + c) * P;
  const u16* Kp = qkv + (size_t)(b * 192 + 64 + c) * P;
  const u16* Vp = qkv + (size_t)(b * 192 + 128 + c) * P;

  float sq = rnsum[b * 128 + c], sk = rnsum[b * 128 + 64 + c];
  float sc = scale[c >> 3] / (fmaxf(sqrtf(sq), 1e-12f) * fmaxf(sqrtf(sk), 1e-12f));

  f32x4 Sa[4][4];
  f32x4 zero = {0.f, 0.f, 0.f, 0.f};
#pragma unroll
  for (int i = 0; i < 4; ++i)
#pragma unroll
    for (int j = 0; j < 4; ++j) Sa[i][j] = zero;

  // ---- S phase: 8 k-windows of 32 ----
  if (dir == 0) {
    for (int yw = 0; yw < 8; ++yw) {
      int y0 = yw << 5;
      bf16x8 af[4], bfr[4];
#pragma unroll
      for (int i = 0; i < 4; ++i)
        af[i] = *(const bf16x8*)&Qp[(size_t)(r0 + i * 16 + cl) * 256 + y0 + q * 8];
#pragma unroll
      for (int j = 0; j < 4; ++j)
        bfr[j] = *(const bf16x8*)&Kp[(size_t)(w * 64 + j * 16 + cl) * 256 + y0 + q * 8];
      __builtin_amdgcn_s_setprio(1);
#pragma unroll
      for (int i = 0; i < 4; ++i)
#pragma unroll
        for (int j = 0; j < 4; ++j)
          Sa[i][j] = __builtin_amdgcn_mfma_f32_16x16x32_bf16(af[i], bfr[j], Sa[i][j], 0, 0, 0);
      __builtin_amdgcn_s_setprio(0);
    }
  } else {
    // stage K^T (256 cols) + Q^T (64 cols at r0) per window; next window's
    // global loads preloaded into regs so they fly during the MFMA cluster.
    int y2 = t >> 4, colc = t & 15;
    int kkey = (((y2 >> 2) ^ (colc & 3)) << 2) + (y2 & 3);
    int qkey = (((y2 >> 2) ^ ((colc >> 2) & 3)) << 2) + (y2 & 3);
    unsigned KA[8], KB[8], QA[2], QB[2];
    {
      const u16* krp = Kp + (size_t)(2 * y2) * 256 + colc * 16;
      uint4 ka0 = *(const uint4*)krp;
      uint4 ka1 = *(const uint4*)(krp + 8);
      uint4 kb0 = *(const uint4*)(krp + 256);
      uint4 kb1 = *(const uint4*)(krp + 264);
      const u16* qrp = Qp + (size_t)(2 * y2) * 256 + r0 + colc * 4;
      uint2 qa = *(const uint2*)qrp;
      uint2 qb = *(const uint2*)(qrp + 256);
      KA[0] = ka0.x; KA[1] = ka0.y; KA[2] = ka0.z; KA[3] = ka0.w;
      KA[4] = ka1.x; KA[5] = ka1.y; KA[6] = ka1.z; KA[7] = ka1.w;
      KB[0] = kb0.x; KB[1] = kb0.y; KB[2] = kb0.z; KB[3] = kb0.w;
      KB[4] = kb1.x; KB[5] = kb1.y; KB[6] = kb1.z; KB[7] = kb1.w;
      QA[0] = qa.x; QA[1] = qa.y; QB[0] = qb.x; QB[1] = qb.y;
    }
#pragma unroll
    for (int yw = 0; yw < 8; ++yw) {
      bar_lds();  // prior window's LDS reads complete
#pragma unroll
      for (int m = 0; m < 16; ++m) {
        unsigned lo = (m & 1) ? (KA[m >> 1] >> 16) : (KA[m >> 1] & 0xffffu);
        unsigned hi = (m & 1) ? (KB[m >> 1] & 0xffff0000u) : (KB[m >> 1] << 16);
        Tt32[(colc * 16 + m) * 20 + kkey] = lo | hi;
      }
#pragma unroll
      for (int m = 0; m < 4; ++m) {
        unsigned lo = (m & 1) ? (QA[m >> 1] >> 16) : (QA[m >> 1] & 0xffffu);
        unsigned hi = (m & 1) ? (QB[m >> 1] & 0xffff0000u) : (QB[m >> 1] << 16);
        Qt32[(colc * 4 + m) * 20 + qkey] = lo | hi;
      }
      unsigned NKA[8], NKB[8], NQA[2], NQB[2];
      if (yw < 7) {
        int y0 = (yw + 1) << 5;
        const u16* krp = Kp + (size_t)(y0 + 2 * y2) * 256 + colc * 16;
        uint4 ka0 = *(const uint4*)krp;
        uint4 ka1 = *(const uint4*)(krp + 8);
        uint4 kb0 = *(const uint4*)(krp + 256);
        uint4 kb1 = *(const uint4*)(krp + 264);
        const u16* qrp = Qp + (size_t)(y0 + 2 * y2) * 256 + r0 + colc * 4;
        uint2 qa = *(const uint2*)qrp;
        uint2 qb = *(const uint2*)(qrp + 256);
        NKA[0] = ka0.x; NKA[1] = ka0.y; NKA[2] = ka0.z; NKA[3] = ka0.w;
        NKA[4] = ka1.x; NKA[5] = ka1.y; NKA[6] = ka1.z; NKA[7] = ka1.w;
        NKB[0] = kb0.x; NKB[1] = kb0.y; NKB[2] = kb0.z; NKB[3] = kb0.w;
        NKB[4] = kb1.x; NKB[5] = kb1.y; NKB[6] = kb1.z; NKB[7] = kb1.w;
        NQA[0] = qa.x; NQA[1] = qa.y; NQB[0] = qb.x; NQB[1] = qb.y;
      }
      bar_lds();  // staged data visible; next-window loads stay in flight
      bf16x8 af[4], bfr[4];
#pragma unroll
      for (int i = 0; i < 4; ++i)
        af[i] = *(const bf16x8*)&Qt32[(i * 16 + cl) * 20 + ((q ^ i) << 2)];
#pragma unroll
      for (int j = 0; j < 4; ++j) {
        int col = w * 64 + j * 16 + cl;
        bfr[j] = *(const bf16x8*)&Tt32[col * 20 + ((q ^ j) << 2)];
      }
      __builtin_amdgcn_s_setprio(1);
#pragma unroll
      for (int i = 0; i < 4; ++i)
#pragma unroll
        for (int j = 0; j < 4; ++j)
          Sa[i][j] = __builtin_amdgcn_mfma_f32_16x16x32_bf16(af[i], bfr[j], Sa[i][j], 0, 0, 0);
      __builtin_amdgcn_s_setprio(0);
      if (yw < 7) {
#pragma unroll
        for (int m = 0; m < 8; ++m) { KA[m] = NKA[m]; KB[m] = NKB[m]; }
        QA[0] = NQA[0]; QA[1] = NQA[1]; QB[0] = NQB[0]; QB[1] = NQB[1];
      }
    }
    __syncthreads();  // close Qt32/Tt32 reads before red/Pls writes
  }

  // ---- softmax over cols, NO max pass: |S*sc| <= scale ----
  float sm[4][4];
#pragma unroll
  for (int i = 0; i < 4; ++i)
#pragma unroll
    for (int r = 0; r < 4; ++r) {
      float s0 = 0.f;
#pragma unroll
      for (int j = 0; j < 4; ++j) {
        float e = __expf(Sa[i][j][r] * sc);
        Sa[i][j][r] = e;
        s0 += e;
      }
#pragma unroll
      for (int off = 1; off < 16; off <<= 1) s0 += __shfl_xor(s0, off);
      sm[i][r] = s0;
    }
  if (cl == 0) {
#pragma unroll
    for (int i = 0; i < 4; ++i)
#pragma unroll
      for (int r = 0; r < 4; ++r) red[w * 64 + i * 16 + q * 4 + r] = sm[i][r];
  }
  __syncthreads();
#pragma unroll
  for (int i = 0; i < 4; ++i)
#pragma unroll
    for (int r = 0; r < 4; ++r) {
      int rho = i * 16 + q * 4 + r;
      sm[i][r] = 1.f / (red[rho] + red[64 + rho] + red[128 + rho] + red[192 + rho]);
    }
  // P -> Pls row-major [row][z]
#pragma unroll
  for (int i = 0; i < 4; ++i)
#pragma unroll
    for (int r = 0; r < 4; ++r) {
      int rho = i * 16 + q * 4 + r;
#pragma unroll
      for (int j = 0; j < 4; ++j)
        Pls[rho * 264 + w * 64 + j * 16 + cl] = f2bf(Sa[i][j][r] * sm[i][r]);
    }
  __syncthreads();

  // ---- O = P V over 8 z-windows ----
  f32x4 Oa[4][4];
#pragma unroll
  for (int i = 0; i < 4; ++i)
#pragma unroll
    for (int j = 0; j < 4; ++j) Oa[i][j] = zero;

  if (dir == 0) {
    // stage V^T per window, next window's loads preloaded into regs.
    int z2 = t >> 4, colc = t & 15;
    int zlo = z2 & 3;
    int wkey = (((z2 >> 2) ^ (colc & 3)) << 2) + zlo;
    unsigned A[8], Bv[8];
    {
      const u16* rp = Vp + (size_t)(2 * z2) * 256 + colc * 16;
      uint4 a0 = *(const uint4*)rp;
      uint4 a1 = *(const uint4*)(rp + 8);
      uint4 c0 = *(const uint4*)(rp + 256);
      uint4 c1 = *(const uint4*)(rp + 264);
      A[0] = a0.x; A[1] = a0.y; A[2] = a0.z; A[3] = a0.w;
      A[4] = a1.x; A[5] = a1.y; A[6] = a1.z; A[7] = a1.w;
      Bv[0] = c0.x; Bv[1] = c0.y; Bv[2] = c0.z; Bv[3] = c0.w;
      Bv[4] = c1.x; Bv[5] = c1.y; Bv[6] = c1.z; Bv[7] = c1.w;
    }
#pragma unroll
    for (int zw = 0; zw < 8; ++zw) {
      int z0 = zw << 5;
      bar_lds();  // previous window's Vt reads complete
#pragma unroll
      for (int m = 0; m < 16; ++m) {
        unsigned lo = (m & 1) ? (A[m >> 1] >> 16) : (A[m >> 1] & 0xffffu);
        unsigned hi = (m & 1) ? (Bv[m >> 1] & 0xffff0000u) : (Bv[m >> 1] << 16);
        Tt32[(colc * 16 + m) * 20 + wkey] = lo | hi;
      }
      unsigned NA[8], NBv[8];
      if (zw < 7) {
        const u16* rp = Vp + (size_t)(z0 + 32 + 2 * z2) * 256 + colc * 16;
        uint4 a0 = *(const uint4*)rp;
        uint4 a1 = *(const uint4*)(rp + 8);
        uint4 c0 = *(const uint4*)(rp + 256);
        uint4 c1 = *(const uint4*)(rp + 264);
        NA[0] = a0.x; NA[1] = a0.y; NA[2] = a0.z; NA[3] = a0.w;
        NA[4] = a1.x; NA[5] = a1.y; NA[6] = a1.z; NA[7] = a1.w;
        NBv[0] = c0.x; NBv[1] = c0.y; NBv[2] = c0.z; NBv[3] = c0.w;
        NBv[4] = c1.x; NBv[5] = c1.y; NBv[6] = c1.z; NBv[7] = c1.w;
      }
      bar_lds();  // staged data visible; next-window loads stay in flight
      bf16x8 af[4], bfr[4];
#pragma unroll
      for (int i = 0; i < 4; ++i)
        af[i] = *(const bf16x8*)&Pls[(i * 16 + cl) * 264 + z0 + q * 8];
#pragma unroll
      for (int j = 0; j < 4; ++j) {
        int col = w * 64 + j * 16 + cl;
        bfr[j] = *(const bf16x8*)&Tt32[col * 20 + ((q ^ j) << 2)];
      }
      __builtin_amdgcn_s_setprio(1);
#pragma unroll
      for (int i = 0; i < 4; ++i)
#pragma unroll
        for (int j = 0; j < 4; ++j)
          Oa[i][j] = __builtin_amdgcn_mfma_f32_16x16x32_bf16(af[i], bfr[j], Oa[i][j], 0, 0, 0);
      __builtin_amdgcn_s_setprio(0);
      if (zw < 7) {
#pragma unroll
        for (int m = 0; m < 8; ++m) { A[m] = NA[m]; Bv[m] = NBv[m]; }
      }
    }
    u16* op = oh + (size_t)(b * 64 + c) * P;
#pragma unroll
    for (int i = 0; i < 4; ++i)
#pragma unroll
      for (int j = 0; j < 4; ++j)
#pragma unroll
        for (int r = 0; r < 4; ++r)
          op[(size_t)(r0 + i * 16 + q * 4 + r) * 256 + w * 64 + j * 16 + cl] = f2bf(Oa[i][j][r]);
  } else {
    for (int zw = 0; zw < 8; ++zw) {
      int z0 = zw << 5;
      bf16x8 af[4], bfr[4];
#pragma unroll
      for (int i = 0; i < 4; ++i)
        af[i] = *(const bf16x8*)&Pls[(i * 16 + cl) * 264 + z0 + q * 8];
#pragma unroll
      for (int j = 0; j < 4; ++j)
        bfr[j] = *(const bf16x8*)&Vp[(size_t)(w * 64 + j * 16 + cl) * 256 + z0 + q * 8];
      __builtin_amdgcn_s_setprio(1);
#pragma unroll
      for (int i = 0; i < 4; ++i)
#pragma unroll
        for (int j = 0; j < 4; ++j)
          Oa[i][j] = __builtin_amdgcn_mfma_f32_16x16x32_bf16(af[i], bfr[j], Oa[i][j], 0, 0, 0);
      __builtin_amdgcn_s_setprio(0);
    }
    // transposed store via LDS (Pls dead; barrier-protected)
    u16* op = ov + (size_t)(b * 64 + c) * P;
    __syncthreads();
    for (int h = 0; h < 2; ++h) {
#pragma unroll
      for (int ii = 0; ii < 2; ++ii) {
        int i = h * 2 + ii;
#pragma unroll
        for (int j = 0; j < 4; ++j)
#pragma unroll
          for (int r = 0; r < 4; ++r)
            Osf[(ii * 16 + q * 4 + r) * 260 + w * 64 + j * 16 + cl] = Oa[i][j][r];
      }
      __syncthreads();
      int rr = t & 31, xb = t >> 5;
      for (int xx = 0; xx < 32; ++xx) {
        int xcol = xx * 8 + xb;
        op[(size_t)xcol * 256 + r0 + h * 32 + rr] = f2bf(Osf[rr * 260 + xcol]);
      }
      __syncthreads();
    }
  }
}

// ---------------- mix (cw,aw) + 64x64 projection GEMM, in place on d_out ----------------
__global__ __launch_bounds__(256) void k_final(
    float* __restrict__ dout, const u16* __restrict__ oh, const u16* __restrict__ ov,
    const float* __restrict__ wp, const float* __restrict__ bp,
    const float* __restrict__ cwaw) {
  __shared__ u16 Ms[256 * 72];  // B^T: [px][ch]
  __shared__ u16 Ws[64 * 72];   // A: [row][ch]
  int t = threadIdx.x;
  int b = blockIdx.x >> 8;
  int p0 = (blockIdx.x & 255) << 8;
  float cw = cwaw[b * 2], aw = cwaw[b * 2 + 1];

  {
    int row = t >> 2, c0 = (t & 3) << 4;
    const float* src = wp + row * 64 + c0;
    unsigned pk[8];
#pragma unroll
    for (int j = 0; j < 8; ++j)
      pk[j] = (unsigned)f2bf(src[2 * j]) | ((unsigned)f2bf(src[2 * j + 1]) << 16);
    uint4* dst = (uint4*)&Ws[row * 72 + c0];
    dst[0] = make_uint4(pk[0], pk[1], pk[2], pk[3]);
    dst[1] = make_uint4(pk[4], pk[5], pk[6], pk[7]);
  }
  // stage mixed m = cw*conv + aw*(oh+ov): 2 px/thread, 32 channel iters
  {
    int p2 = (t & 127) * 2, ch0 = (t >> 7) * 32;
    size_t base = ((size_t)(b * 64 + ch0) << 16) + p0 + p2;
    for (int cc = 0; cc < 32; ++cc) {
      size_t off = base + ((size_t)cc << 16);
      float2 dv = *(const float2*)&dout[off];
      unsigned ohv = *(const unsigned*)&oh[off];
      unsigned ovv = *(const unsigned*)&ov[off];
      int c = ch0 + cc;
      float m0 = cw * dv.x + aw * (bf2f((u16)(ohv & 0xffff)) + bf2f((u16)(ovv & 0xffff)));
      float m1 = cw * dv.y + aw * (bf2f((u16)(ohv >> 16)) + bf2f((u16)(ovv >> 16)));
      Ms[p2 * 72 + c] = f2bf(m0);
      Ms[(p2 + 1) * 72 + c] = f2bf(m1);
    }
  }
  __syncthreads();

  int w = t >> 6, l = t & 63, q = l >> 4, cl = l & 15;
  bf16x8 af0 = *(const bf16x8*)&Ws[(w * 16 + cl) * 72 + q * 8];
  bf16x8 af1 = *(const bf16x8*)&Ws[(w * 16 + cl) * 72 + 32 + q * 8];

  f32x4 acc[16];
  f32x4 zero = {0.f, 0.f, 0.f, 0.f};
#pragma unroll
  for (int j = 0; j < 16; ++j) acc[j] = zero;

  for (int j = 0; j < 16; ++j) {
    bf16x8 b0 = *(const bf16x8*)&Ms[(j * 16 + cl) * 72 + q * 8];
    bf16x8 b1 = *(const bf16x8*)&Ms[(j * 16 + cl) * 72 + 32 + q * 8];
    acc[j] = __builtin_amdgcn_mfma_f32_16x16x32_bf16(af0, b0, acc[j], 0, 0, 0);
    acc[j] = __builtin_amdgcn_mfma_f32_16x16x32_bf16(af1, b1, acc[j], 0, 0, 0);
  }

  float bpv[4];
#pragma unroll
  for (int r = 0; r < 4; ++r) bpv[r] = bp[w * 16 + q * 4 + r];
  float* outb = dout + ((size_t)(b * 64) << 16) + p0;
#pragma unroll
  for (int r = 0; r < 4; ++r) {
    float* orow = outb + ((size_t)(w * 16 + q * 4 + r) << 16);
#pragma unroll
    for (int j = 0; j < 16; ++j) orow[j * 16 + cl] = acc[j][r] + bpv[r];
  }
}

extern "C" void kernel_launch(void* const* d_in, const int* in_sizes, int n_in,
                              void* d_out, int out_size, void* d_ws, size_t ws_size,
                              hipStream_t stream) {
  const float* x = (const float*)d_in[0];
  const float* w3 = (const float*)d_in[1];
  const float* b3 = (const float*)d_in[2];
  const float* w5 = (const float*)d_in[3];
  const float* b5 = (const float*)d_in[4];
  const float* wqkv = (const float*)d_in[5];
  const float* scale = (const float*)d_in[6];
  const float* g1w = (const float*)d_in[7];
  const float* g1b = (const float*)d_in[8];
  const float* g2w = (const float*)d_in[9];
  const float* g2b = (const float*)d_in[10];
  const float* wp = (const float*)d_in[11];
  const float* bp = (const float*)d_in[12];
  float* out = (float*)d_out;

  char* ws = (char*)d_ws;
  u16* qkv = (u16*)(ws);
  u16* ohb = (u16*)(ws + 100663296ull);
  u16* ovb = (u16*)(ws + 134217728ull);
  float* fs = (float*)(ws + 167772160ull);
  float* gxsum = fs;        // 256
  float* cwaw = fs + 256;   // 8
  float* rnsum = fs + 264;  // 512

  k_zero<<<1, 1024, 0, stream>>>(fs);
  k_qkv<<<2048, 256, 0, stream>>>(x, wqkv, qkv, rnsum);
  k_conv<<<8192, 256, 0, stream>>>(x, w3, b3, w5, b5, out, gxsum);
  k_gate<<<1, 64, 0, stream>>>(gxsum, g1w, g1b, g2w, g2b, cwaw);
  k_attn<<<2048, 256, 0, stream>>>(qkv, rnsum, scale, ohb, ovb);
  k_final<<<1024, 256, 0, stream>>>(out, ohb, ovb, wp, bp, cwaw);
}

// Round 9
// 377.631 us; speedup vs baseline: 1.4136x; 1.4136x over previous
//
#include <hip/hip_runtime.h>
#include <stdint.h>

// CAFormer fused block, MI355X gfx950.
// R12 (on R10=338us proven): R11's k_qkv rnorm fusion serialized on 512-way
// same-address atomics (k_qkv 245us, MfmaUtil 1%). Redo with 16-sharded
// partials rns[16][512] living in d_out (dead until k_conv) -> 32-way
// contention; k_attn sums shards. k_rnorm deleted. All other kernels
// byte-identical to R10. Order: zero,qkv,gx,gate,attn,conv,final.
// ws layout (160 MiB + ~1 KB):
//   qkv bf16 [4][192][65536] @ 0          (100663296 B)
//   oh  bf16 [4][64][65536]  @ 100663296  (33554432 B)
//   ov  bf16                 @ 134217728  (33554432 B)
//   f32 scratch @ 167772160: gxsum[256] cwaw[8]
// d_out head doubles as rns[16][512] f32 between k_zero and k_attn.

typedef unsigned short u16;
typedef __attribute__((ext_vector_type(8))) short bf16x8;
typedef __attribute__((ext_vector_type(4))) float f32x4;

#define DEV static __device__ __forceinline__

DEV u16 f2bf(float f) {
  unsigned u = __float_as_uint(f);
  return (u16)((u + 0x7fffu + ((u >> 16) & 1u)) >> 16);
}
DEV float bf2f(u16 h) { return __uint_as_float(((unsigned)h) << 16); }

// barrier that orders LDS only: lgkmcnt(0) + raw s_barrier. Global loads in
// flight (thread-private regs) are NOT drained, unlike __syncthreads().
DEV void bar_lds() {
  asm volatile("s_waitcnt lgkmcnt(0)" ::: "memory");
  __builtin_amdgcn_s_barrier();
}

// ---------------- zero the rns shard scratch (graph-capture-safe) ----------------
__global__ void k_zero(float* __restrict__ rns) {
  int i = blockIdx.x * 1024 + threadIdx.x;
  if (i < 8192) rns[i] = 0.f;
}

// ---------------- gating: per-(b,c) spatial sum of x ----------------
__global__ void k_gx(const float* __restrict__ x, float* __restrict__ gxsum) {
  int bc = blockIdx.x, t = threadIdx.x;
  const float4* p = (const float4*)(x + ((size_t)bc << 16));
  float s = 0.f;
  for (int i = 0; i < 64; ++i) { float4 v = p[t + 256 * i]; s += v.x + v.y + v.z + v.w; }
  for (int off = 32; off; off >>= 1) s += __shfl_down(s, off);
  __shared__ float lds[4];
  if ((t & 63) == 0) lds[t >> 6] = s;
  __syncthreads();
  if (t == 0) gxsum[bc] = lds[0] + lds[1] + lds[2] + lds[3];
}

// ---------------- gating MLP -> cw/aw per batch ----------------
__global__ void k_gate(const float* __restrict__ gxsum, const float* __restrict__ g1w,
                       const float* __restrict__ g1b, const float* __restrict__ g2w,
                       const float* __restrict__ g2b, float* __restrict__ cwaw) {
  __shared__ float h1[4][16];
  int t = threadIdx.x;
  int b = t >> 4, j = t & 15;
  float a = g1b[j];
  for (int c = 0; c < 64; ++c) a += g1w[j * 64 + c] * gxsum[b * 64 + c] * (1.f / 65536.f);
  h1[b][j] = fmaxf(a, 0.f);
  __syncthreads();
  if (t < 4) {
    float l0 = g2b[0], l1 = g2b[1];
    for (int k = 0; k < 16; ++k) { l0 += g2w[k] * h1[t][k]; l1 += g2w[16 + k] * h1[t][k]; }
    float m = fmaxf(l0, l1);
    float e0 = __expf(l0 - m), e1 = __expf(l1 - m);
    float inv = 1.f / (e0 + e1);
    cwaw[t * 2 + 0] = e0 * inv;  // conv weight
    cwaw[t * 2 + 1] = e1 * inv;  // attn weight
  }
}

// ---------------- qkv projection GEMM + 16-sharded rnorm partials ----------------
__global__ __launch_bounds__(256) void k_qkv(const float* __restrict__ x,
                                             const float* __restrict__ wqkv,
                                             u16* __restrict__ qkv,
                                             float* __restrict__ rns) {
  __shared__ u16 Ws[192 * 72];  // A: [row][ch], stride 72 shorts
  __shared__ u16 Xs[128 * 72];  // B^T: [px][ch]
  int t = threadIdx.x;
  int b = blockIdx.x >> 9;
  int p0 = (blockIdx.x & 511) << 7;

  // stage wqkv (192x64 fp32 -> bf16)
  {
    int row = t >> 2, c0 = (t & 3) << 4;
#pragma unroll
    for (int i = 0; i < 3; ++i) {
      int r = i * 64 + row;
      const float* src = wqkv + r * 64 + c0;
      unsigned pk[8];
#pragma unroll
      for (int j = 0; j < 8; ++j)
        pk[j] = (unsigned)f2bf(src[2 * j]) | ((unsigned)f2bf(src[2 * j + 1]) << 16);
      uint4* dst = (uint4*)&Ws[r * 72 + c0];
      dst[0] = make_uint4(pk[0], pk[1], pk[2], pk[3]);
      dst[1] = make_uint4(pk[4], pk[5], pk[6], pk[7]);
    }
  }
  // stage x tile: 64ch x 128px, transposed -> Xs[px][ch]
  {
    int p = t & 127, ch = t >> 7;
    const float* xb = x + ((size_t)(b * 64) << 16) + p0 + p;
#pragma unroll
    for (int i = 0; i < 32; ++i) {
      int c = 2 * i + ch;
      Xs[p * 72 + c] = f2bf(xb[(size_t)c << 16]);
    }
  }
  __syncthreads();

  int w = t >> 6, l = t & 63, q = l >> 4, cl = l & 15;
  bf16x8 af[3][2];
#pragma unroll
  for (int g = 0; g < 3; ++g)
#pragma unroll
    for (int k = 0; k < 2; ++k)
      af[g][k] = *(const bf16x8*)&Ws[(w * 48 + g * 16 + cl) * 72 + k * 32 + q * 8];

  f32x4 acc[3][8];
  f32x4 zero = {0.f, 0.f, 0.f, 0.f};
#pragma unroll
  for (int g = 0; g < 3; ++g)
#pragma unroll
    for (int j = 0; j < 8; ++j) acc[g][j] = zero;

  for (int j = 0; j < 8; ++j) {
    bf16x8 b0 = *(const bf16x8*)&Xs[(j * 16 + cl) * 72 + q * 8];
    bf16x8 b1 = *(const bf16x8*)&Xs[(j * 16 + cl) * 72 + 32 + q * 8];
#pragma unroll
    for (int g = 0; g < 3; ++g) {
      acc[g][j] = __builtin_amdgcn_mfma_f32_16x16x32_bf16(af[g][0], b0, acc[g][j], 0, 0, 0);
      acc[g][j] = __builtin_amdgcn_mfma_f32_16x16x32_bf16(af[g][1], b1, acc[g][j], 0, 0, 0);
    }
  }
  u16* outb = qkv + ((size_t)(b * 192) << 16) + p0;
  for (int g = 0; g < 3; ++g) {
    int rowb = w * 48 + g * 16 + q * 4;
#pragma unroll
    for (int r = 0; r < 4; ++r) {
      u16* orow = outb + ((size_t)(rowb + r) << 16);
#pragma unroll
      for (int j = 0; j < 8; ++j) orow[j * 16 + cl] = f2bf(acc[g][j][r]);
    }
  }
  // rnorm partials: sum of squares of fp32 acc for q,k rows (row<128),
  // 16-sharded by blockIdx to keep same-address contention at 32.
  float* rn = rns + (blockIdx.x & 15) * 512 + b * 128;
#pragma unroll
  for (int g = 0; g < 3; ++g) {
    int rowb = w * 48 + g * 16 + q * 4;
    if (rowb < 128) {
#pragma unroll
      for (int r = 0; r < 4; ++r) {
        float s = 0.f;
#pragma unroll
        for (int j = 0; j < 8; ++j) { float v = acc[g][j][r]; s += v * v; }
#pragma unroll
        for (int off = 1; off < 16; off <<= 1) s += __shfl_xor(s, off);
        if (cl == 0) atomicAdd(&rn[rowb + r], s);
      }
    }
  }
}

// ---------------- depthwise 3x3+5x5 conv, branch-free padded tile ----------------
__global__ void k_conv(const float* __restrict__ x, const float* __restrict__ w3,
                       const float* __restrict__ b3, const float* __restrict__ w5,
                       const float* __restrict__ b5, const float* __restrict__ cwaw,
                       float* __restrict__ outmix) {
  int rt = blockIdx.x & 31, bc = blockIdx.x >> 5, c = bc & 63, b = bc >> 6;
  int r0 = rt * 8;
  const float* xp = x + ((size_t)bc << 16);
  __shared__ float xs[12][260];  // padded: col g maps to index g+2; 0..1,258..259 zero
  int y = threadIdx.x;
  for (int rr = 0; rr < 12; ++rr) {
    int gr = r0 - 2 + rr;
    xs[rr][y + 2] = (gr >= 0 && gr < 256) ? xp[(size_t)gr * 256 + y] : 0.f;
  }
  if (y < 2) {
    for (int rr = 0; rr < 12; ++rr) { xs[rr][y] = 0.f; xs[rr][258 + y] = 0.f; }
  }
  __syncthreads();
  float W3[9], W5[25];
#pragma unroll
  for (int i = 0; i < 9; ++i) W3[i] = w3[c * 9 + i];
#pragma unroll
  for (int i = 0; i < 25; ++i) W5[i] = w5[c * 25 + i];
  float bias = b3[c] + b5[c];
  float cw = cwaw[b * 2];
  float* op = outmix + ((size_t)bc << 16);
  for (int k = 0; k < 8; ++k) {
    float a = bias;
#pragma unroll
    for (int di = 0; di < 3; ++di)
#pragma unroll
      for (int dj = 0; dj < 3; ++dj)
        a += W3[di * 3 + dj] * xs[k + 1 + di][y + 1 + dj];
#pragma unroll
    for (int di = 0; di < 5; ++di)
#pragma unroll
      for (int dj = 0; dj < 5; ++dj)
        a += W5[di * 5 + dj] * xs[k + di][y + dj];
    op[(size_t)(r0 + k) * 256 + y] = cw * a;
  }
}

// ---------------- axial attention, MFMA bf16, 64-row tiles, pipelined staging ----------------
// dir0: S direct (native Q,K rows); PV stages V^T per z-window (preloaded regs).
// dir1: S stages Q^T + K^T per y-window (preloaded regs); PV direct.
__global__ __launch_bounds__(256) void k_attn(
    const u16* __restrict__ qkv, const float* __restrict__ rns,
    const float* __restrict__ scale, u16* __restrict__ oh, u16* __restrict__ ov) {
  __shared__ __align__(16) unsigned char smem[54272];
  u16* Pls = (u16*)smem;                       // [64][264] bf16 (33792 B)
  unsigned* Qt32 = (unsigned*)smem;            // [64][20] u32 (5120 B; dir1 S, Pls dead)
  float* red = (float*)(smem + 33792);         // [4][64] f32
  unsigned* Tt32 = (unsigned*)(smem + 33792);  // [256][20] u32 (Kt dir1-S / Vt dir0-PV)
  float* Osf = (float*)smem;                   // [32][260] f32 (dir1 store; Pls dead)

  int t = threadIdx.x;
  int w = t >> 6, l = t & 63, q = l >> 4, cl = l & 15;
  // XCD-aware bijective swizzle: one channel's 8 blocks (4 rt x 2 dir) are
  // consecutive in idx -> same XCD -> planes shared in that XCD's L2.
  int idx = (blockIdx.x & 7) * 256 + (blockIdx.x >> 3);
  int rt = idx & 3, dir = (idx >> 2) & 1, c = (idx >> 3) & 63, b = idx >> 9;
  int r0 = rt << 6;

  const size_t P = 65536;
  const u16* Qp = qkv + (size_t)(b * 192 + c) * P;
  const u16* Kp = qkv + (size_t)(b * 192 + 64 + c) * P;
  const u16* Vp = qkv + (size_t)(b * 192 + 128 + c) * P;

  float sq = 0.f, sk = 0.f;
#pragma unroll
  for (int s = 0; s < 16; ++s) {
    sq += rns[s * 512 + b * 128 + c];
    sk += rns[s * 512 + b * 128 + 64 + c];
  }
  float sc = scale[c >> 3] / (fmaxf(sqrtf(sq), 1e-12f) * fmaxf(sqrtf(sk), 1e-12f));

  f32x4 Sa[4][4];
  f32x4 zero = {0.f, 0.f, 0.f, 0.f};
#pragma unroll
  for (int i = 0; i < 4; ++i)
#pragma unroll
    for (int j = 0; j < 4; ++j) Sa[i][j] = zero;

  // ---- S phase: 8 k-windows of 32 ----
  if (dir == 0) {
    for (int yw = 0; yw < 8; ++yw) {
      int y0 = yw << 5;
      bf16x8 af[4], bfr[4];
#pragma unroll
      for (int i = 0; i < 4; ++i)
        af[i] = *(const bf16x8*)&Qp[(size_t)(r0 + i * 16 + cl) * 256 + y0 + q * 8];
#pragma unroll
      for (int j = 0; j < 4; ++j)
        bfr[j] = *(const bf16x8*)&Kp[(size_t)(w * 64 + j * 16 + cl) * 256 + y0 + q * 8];
      __builtin_amdgcn_s_setprio(1);
#pragma unroll
      for (int i = 0; i < 4; ++i)
#pragma unroll
        for (int j = 0; j < 4; ++j)
          Sa[i][j] = __builtin_amdgcn_mfma_f32_16x16x32_bf16(af[i], bfr[j], Sa[i][j], 0, 0, 0);
      __builtin_amdgcn_s_setprio(0);
    }
  } else {
    // stage K^T (256 cols) + Q^T (64 cols at r0) per window; next window's
    // global loads preloaded into regs so they fly during the MFMA cluster.
    int y2 = t >> 4, colc = t & 15;
    int kkey = (((y2 >> 2) ^ (colc & 3)) << 2) + (y2 & 3);
    int qkey = (((y2 >> 2) ^ ((colc >> 2) & 3)) << 2) + (y2 & 3);
    unsigned KA[8], KB[8], QA[2], QB[2];
    {
      const u16* krp = Kp + (size_t)(2 * y2) * 256 + colc * 16;
      uint4 ka0 = *(const uint4*)krp;
      uint4 ka1 = *(const uint4*)(krp + 8);
      uint4 kb0 = *(const uint4*)(krp + 256);
      uint4 kb1 = *(const uint4*)(krp + 264);
      const u16* qrp = Qp + (size_t)(2 * y2) * 256 + r0 + colc * 4;
      uint2 qa = *(const uint2*)qrp;
      uint2 qb = *(const uint2*)(qrp + 256);
      KA[0] = ka0.x; KA[1] = ka0.y; KA[2] = ka0.z; KA[3] = ka0.w;
      KA[4] = ka1.x; KA[5] = ka1.y; KA[6] = ka1.z; KA[7] = ka1.w;
      KB[0] = kb0.x; KB[1] = kb0.y; KB[2] = kb0.z; KB[3] = kb0.w;
      KB[4] = kb1.x; KB[5] = kb1.y; KB[6] = kb1.z; KB[7] = kb1.w;
      QA[0] = qa.x; QA[1] = qa.y; QB[0] = qb.x; QB[1] = qb.y;
    }
#pragma unroll
    for (int yw = 0; yw < 8; ++yw) {
      bar_lds();  // prior window's LDS reads complete
#pragma unroll
      for (int m = 0; m < 16; ++m) {
        unsigned lo = (m & 1) ? (KA[m >> 1] >> 16) : (KA[m >> 1] & 0xffffu);
        unsigned hi = (m & 1) ? (KB[m >> 1] & 0xffff0000u) : (KB[m >> 1] << 16);
        Tt32[(colc * 16 + m) * 20 + kkey] = lo | hi;
      }
#pragma unroll
      for (int m = 0; m < 4; ++m) {
        unsigned lo = (m & 1) ? (QA[m >> 1] >> 16) : (QA[m >> 1] & 0xffffu);
        unsigned hi = (m & 1) ? (QB[m >> 1] & 0xffff0000u) : (QB[m >> 1] << 16);
        Qt32[(colc * 4 + m) * 20 + qkey] = lo | hi;
      }
      unsigned NKA[8], NKB[8], NQA[2], NQB[2];
      if (yw < 7) {
        int y0 = (yw + 1) << 5;
        const u16* krp = Kp + (size_t)(y0 + 2 * y2) * 256 + colc * 16;
        uint4 ka0 = *(const uint4*)krp;
        uint4 ka1 = *(const uint4*)(krp + 8);
        uint4 kb0 = *(const uint4*)(krp + 256);
        uint4 kb1 = *(const uint4*)(krp + 264);
        const u16* qrp = Qp + (size_t)(y0 + 2 * y2) * 256 + r0 + colc * 4;
        uint2 qa = *(const uint2*)qrp;
        uint2 qb = *(const uint2*)(qrp + 256);
        NKA[0] = ka0.x; NKA[1] = ka0.y; NKA[2] = ka0.z; NKA[3] = ka0.w;
        NKA[4] = ka1.x; NKA[5] = ka1.y; NKA[6] = ka1.z; NKA[7] = ka1.w;
        NKB[0] = kb0.x; NKB[1] = kb0.y; NKB[2] = kb0.z; NKB[3] = kb0.w;
        NKB[4] = kb1.x; NKB[5] = kb1.y; NKB[6] = kb1.z; NKB[7] = kb1.w;
        NQA[0] = qa.x; NQA[1] = qa.y; NQB[0] = qb.x; NQB[1] = qb.y;
      }
      bar_lds();  // staged data visible; next-window loads stay in flight
      bf16x8 af[4], bfr[4];
#pragma unroll
      for (int i = 0; i < 4; ++i)
        af[i] = *(const bf16x8*)&Qt32[(i * 16 + cl) * 20 + ((q ^ i) << 2)];
#pragma unroll
      for (int j = 0; j < 4; ++j) {
        int col = w * 64 + j * 16 + cl;
        bfr[j] = *(const bf16x8*)&Tt32[col * 20 + ((q ^ j) << 2)];
      }
      __builtin_amdgcn_s_setprio(1);
#pragma unroll
      for (int i = 0; i < 4; ++i)
#pragma unroll
        for (int j = 0; j < 4; ++j)
          Sa[i][j] = __builtin_amdgcn_mfma_f32_16x16x32_bf16(af[i], bfr[j], Sa[i][j], 0, 0, 0);
      __builtin_amdgcn_s_setprio(0);
      if (yw < 7) {
#pragma unroll
        for (int m = 0; m < 8; ++m) { KA[m] = NKA[m]; KB[m] = NKB[m]; }
        QA[0] = NQA[0]; QA[1] = NQA[1]; QB[0] = NQB[0]; QB[1] = NQB[1];
      }
    }
    __syncthreads();  // close Qt32/Tt32 reads before red/Pls writes
  }

  // ---- softmax over cols, NO max pass: |S*sc| <= scale ----
  float sm[4][4];
#pragma unroll
  for (int i = 0; i < 4; ++i)
#pragma unroll
    for (int r = 0; r < 4; ++r) {
      float s0 = 0.f;
#pragma unroll
      for (int j = 0; j < 4; ++j) {
        float e = __expf(Sa[i][j][r] * sc);
        Sa[i][j][r] = e;
        s0 += e;
      }
#pragma unroll
      for (int off = 1; off < 16; off <<= 1) s0 += __shfl_xor(s0, off);
      sm[i][r] = s0;
    }
  if (cl == 0) {
#pragma unroll
    for (int i = 0; i < 4; ++i)
#pragma unroll
      for (int r = 0; r < 4; ++r) red[w * 64 + i * 16 + q * 4 + r] = sm[i][r];
  }
  __syncthreads();
#pragma unroll
  for (int i = 0; i < 4; ++i)
#pragma unroll
    for (int r = 0; r < 4; ++r) {
      int rho = i * 16 + q * 4 + r;
      sm[i][r] = 1.f / (red[rho] + red[64 + rho] + red[128 + rho] + red[192 + rho]);
    }
  // P -> Pls row-major [row][z]
#pragma unroll
  for (int i = 0; i < 4; ++i)
#pragma unroll
    for (int r = 0; r < 4; ++r) {
      int rho = i * 16 + q * 4 + r;
#pragma unroll
      for (int j = 0; j < 4; ++j)
        Pls[rho * 264 + w * 64 + j * 16 + cl] = f2bf(Sa[i][j][r] * sm[i][r]);
    }
  __syncthreads();

  // ---- O = P V over 8 z-windows ----
  f32x4 Oa[4][4];
#pragma unroll
  for (int i = 0; i < 4; ++i)
#pragma unroll
    for (int j = 0; j < 4; ++j) Oa[i][j] = zero;

  if (dir == 0) {
    // stage V^T per window, next window's loads preloaded into regs.
    int z2 = t >> 4, colc = t & 15;
    int zlo = z2 & 3;
    int wkey = (((z2 >> 2) ^ (colc & 3)) << 2) + zlo;
    unsigned A[8], Bv[8];
    {
      const u16* rp = Vp + (size_t)(2 * z2) * 256 + colc * 16;
      uint4 a0 = *(const uint4*)rp;
      uint4 a1 = *(const uint4*)(rp + 8);
      uint4 c0 = *(const uint4*)(rp + 256);
      uint4 c1 = *(const uint4*)(rp + 264);
      A[0] = a0.x; A[1] = a0.y; A[2] = a0.z; A[3] = a0.w;
      A[4] = a1.x; A[5] = a1.y; A[6] = a1.z; A[7] = a1.w;
      Bv[0] = c0.x; Bv[1] = c0.y; Bv[2] = c0.z; Bv[3] = c0.w;
      Bv[4] = c1.x; Bv[5] = c1.y; Bv[6] = c1.z; Bv[7] = c1.w;
    }
#pragma unroll
    for (int zw = 0; zw < 8; ++zw) {
      int z0 = zw << 5;
      bar_lds();  // previous window's Vt reads complete
#pragma unroll
      for (int m = 0; m < 16; ++m) {
        unsigned lo = (m & 1) ? (A[m >> 1] >> 16) : (A[m >> 1] & 0xffffu);
        unsigned hi = (m & 1) ? (Bv[m >> 1] & 0xffff0000u) : (Bv[m >> 1] << 16);
        Tt32[(colc * 16 + m) * 20 + wkey] = lo | hi;
      }
      unsigned NA[8], NBv[8];
      if (zw < 7) {
        const u16* rp = Vp + (size_t)(z0 + 32 + 2 * z2) * 256 + colc * 16;
        uint4 a0 = *(const uint4*)rp;
        uint4 a1 = *(const uint4*)(rp + 8);
        uint4 c0 = *(const uint4*)(rp + 256);
        uint4 c1 = *(const uint4*)(rp + 264);
        NA[0] = a0.x; NA[1] = a0.y; NA[2] = a0.z; NA[3] = a0.w;
        NA[4] = a1.x; NA[5] = a1.y; NA[6] = a1.z; NA[7] = a1.w;
        NBv[0] = c0.x; NBv[1] = c0.y; NBv[2] = c0.z; NBv[3] = c0.w;
        NBv[4] = c1.x; NBv[5] = c1.y; NBv[6] = c1.z; NBv[7] = c1.w;
      }
      bar_lds();  // staged data visible; next-window loads stay in flight
      bf16x8 af[4], bfr[4];
#pragma unroll
      for (int i = 0; i < 4; ++i)
        af[i] = *(const bf16x8*)&Pls[(i * 16 + cl) * 264 + z0 + q * 8];
#pragma unroll
      for (int j = 0; j < 4; ++j) {
        int col = w * 64 + j * 16 + cl;
        bfr[j] = *(const bf16x8*)&Tt32[col * 20 + ((q ^ j) << 2)];
      }
      __builtin_amdgcn_s_setprio(1);
#pragma unroll
      for (int i = 0; i < 4; ++i)
#pragma unroll
        for (int j = 0; j < 4; ++j)
          Oa[i][j] = __builtin_amdgcn_mfma_f32_16x16x32_bf16(af[i], bfr[j], Oa[i][j], 0, 0, 0);
      __builtin_amdgcn_s_setprio(0);
      if (zw < 7) {
#pragma unroll
        for (int m = 0; m < 8; ++m) { A[m] = NA[m]; Bv[m] = NBv[m]; }
      }
    }
    u16* op = oh + (size_t)(b * 64 + c) * P;
#pragma unroll
    for (int i = 0; i < 4; ++i)
#pragma unroll
      for (int j = 0; j < 4; ++j)
#pragma unroll
        for (int r = 0; r < 4; ++r)
          op[(size_t)(r0 + i * 16 + q * 4 + r) * 256 + w * 64 + j * 16 + cl] = f2bf(Oa[i][j][r]);
  } else {
    for (int zw = 0; zw < 8; ++zw) {
      int z0 = zw << 5;
      bf16x8 af[4], bfr[4];
#pragma unroll
      for (int i = 0; i < 4; ++i)
        af[i] = *(const bf16x8*)&Pls[(i * 16 + cl) * 264 + z0 + q * 8];
#pragma unroll
      for (int j = 0; j < 4; ++j)
        bfr[j] = *(const bf16x8*)&Vp[(size_t)(w * 64 + j * 16 + cl) * 256 + z0 + q * 8];
      __builtin_amdgcn_s_setprio(1);
#pragma unroll
      for (int i = 0; i < 4; ++i)
#pragma unroll
        for (int j = 0; j < 4; ++j)
          Oa[i][j] = __builtin_amdgcn_mfma_f32_16x16x32_bf16(af[i], bfr[j], Oa[i][j], 0, 0, 0);
      __builtin_amdgcn_s_setprio(0);
    }
    // transposed store via LDS (Pls dead; barrier-protected)
    u16* op = ov + (size_t)(b * 64 + c) * P;
    __syncthreads();
    for (int h = 0; h < 2; ++h) {
#pragma unroll
      for (int ii = 0; ii < 2; ++ii) {
        int i = h * 2 + ii;
#pragma unroll
        for (int j = 0; j < 4; ++j)
#pragma unroll
          for (int r = 0; r < 4; ++r)
            Osf[(ii * 16 + q * 4 + r) * 260 + w * 64 + j * 16 + cl] = Oa[i][j][r];
      }
      __syncthreads();
      int rr = t & 31, xb = t >> 5;
      for (int xx = 0; xx < 32; ++xx) {
        int xcol = xx * 8 + xb;
        op[(size_t)xcol * 256 + r0 + h * 32 + rr] = f2bf(Osf[rr * 260 + xcol]);
      }
      __syncthreads();
    }
  }
}

// ---------------- mix + 64x64 projection as MFMA GEMM, in place on d_out ----------------
__global__ __launch_bounds__(256) void k_final(
    float* __restrict__ dout, const u16* __restrict__ oh, const u16* __restrict__ ov,
    const float* __restrict__ wp, const float* __restrict__ bp,
    const float* __restrict__ cwaw) {
  __shared__ u16 Ms[256 * 72];  // B^T: [px][ch]
  __shared__ u16 Ws[64 * 72];   // A: [row][ch]
  int t = threadIdx.x;
  int b = blockIdx.x >> 8;
  int p0 = (blockIdx.x & 255) << 8;
  float aw = cwaw[b * 2 + 1];

  {
    int row = t >> 2, c0 = (t & 3) << 4;
    const float* src = wp + row * 64 + c0;
    unsigned pk[8];
#pragma unroll
    for (int j = 0; j < 8; ++j)
      pk[j] = (unsigned)f2bf(src[2 * j]) | ((unsigned)f2bf(src[2 * j + 1]) << 16);
    uint4* dst = (uint4*)&Ws[row * 72 + c0];
    dst[0] = make_uint4(pk[0], pk[1], pk[2], pk[3]);
    dst[1] = make_uint4(pk[4], pk[5], pk[6], pk[7]);
  }
  {
    size_t base = ((size_t)(b * 64) << 16) + p0 + t;
    for (int c = 0; c < 64; ++c) {
      size_t off = base + ((size_t)c << 16);
      float m = dout[off] + aw * (bf2f(oh[off]) + bf2f(ov[off]));
      Ms[t * 72 + c] = f2bf(m);
    }
  }
  __syncthreads();

  int w = t >> 6, l = t & 63, q = l >> 4, cl = l & 15;
  bf16x8 af0 = *(const bf16x8*)&Ws[(w * 16 + cl) * 72 + q * 8];
  bf16x8 af1 = *(const bf16x8*)&Ws[(w * 16 + cl) * 72 + 32 + q * 8];

  f32x4 acc[16];
  f32x4 zero = {0.f, 0.f, 0.f, 0.f};
#pragma unroll
  for (int j = 0; j < 16; ++j) acc[j] = zero;

  for (int j = 0; j < 16; ++j) {
    bf16x8 b0 = *(const bf16x8*)&Ms[(j * 16 + cl) * 72 + q * 8];
    bf16x8 b1 = *(const bf16x8*)&Ms[(j * 16 + cl) * 72 + 32 + q * 8];
    acc[j] = __builtin_amdgcn_mfma_f32_16x16x32_bf16(af0, b0, acc[j], 0, 0, 0);
    acc[j] = __builtin_amdgcn_mfma_f32_16x16x32_bf16(af1, b1, acc[j], 0, 0, 0);
  }

  float bpv[4];
#pragma unroll
  for (int r = 0; r < 4; ++r) bpv[r] = bp[w * 16 + q * 4 + r];
  float* outb = dout + ((size_t)(b * 64) << 16) + p0;
#pragma unroll
  for (int r = 0; r < 4; ++r) {
    float* orow = outb + ((size_t)(w * 16 + q * 4 + r) << 16);
#pragma unroll
    for (int j = 0; j < 16; ++j) orow[j * 16 + cl] = acc[j][r] + bpv[r];
  }
}

extern "C" void kernel_launch(void* const* d_in, const int* in_sizes, int n_in,
                              void* d_out, int out_size, void* d_ws, size_t ws_size,
                              hipStream_t stream) {
  const float* x = (const float*)d_in[0];
  const float* w3 = (const float*)d_in[1];
  const float* b3 = (const float*)d_in[2];
  const float* w5 = (const float*)d_in[3];
  const float* b5 = (const float*)d_in[4];
  const float* wqkv = (const float*)d_in[5];
  const float* scale = (const float*)d_in[6];
  const float* g1w = (const float*)d_in[7];
  const float* g1b = (const float*)d_in[8];
  const float* g2w = (const float*)d_in[9];
  const float* g2b = (const float*)d_in[10];
  const float* wp = (const float*)d_in[11];
  const float* bp = (const float*)d_in[12];
  float* out = (float*)d_out;

  char* ws = (char*)d_ws;
  u16* qkv = (u16*)(ws);
  u16* ohb = (u16*)(ws + 100663296ull);
  u16* ovb = (u16*)(ws + 134217728ull);
  float* fs = (float*)(ws + 167772160ull);
  float* gxsum = fs;       // 256
  float* cwaw = fs + 256;  // 8
  float* rns = (float*)d_out;  // [16][512] f32 shards, dead until k_conv

  k_zero<<<8, 1024, 0, stream>>>(rns);
  k_qkv<<<2048, 256, 0, stream>>>(x, wqkv, qkv, rns);
  k_gx<<<256, 256, 0, stream>>>(x, gxsum);
  k_gate<<<1, 64, 0, stream>>>(gxsum, g1w, g1b, g2w, g2b, cwaw);
  k_attn<<<2048, 256, 0, stream>>>(qkv, rns, scale, ohb, ovb);
  k_conv<<<8192, 256, 0, stream>>>(x, w3, b3, w5, b5, cwaw, out);
  k_final<<<1024, 256, 0, stream>>>(out, ohb, ovb, wp, bp, cwaw);
}